// Round 13
// baseline (240.177 us; speedup 1.0000x reference)
//
#include <hip/hip_runtime.h>
#include <math.h>

// ---------------------------------------------------------------------------
// Intra_graph forward, MI355X. Round 13: R12 (best, 224.3us) + ONE delta:
//  * k_gcA and the z2-GEMM (both pure functions of mu, independent) merged
//    into one launch k_gcAz2 (blocks 0-27: gcA; 32-95: z2). k_zdual becomes
//    z1-only k_zg. 13 -> 12 launches.
// R6/R8 forensics exonerated this merge (their regressions were EM-grid /
// nt-epilogue, both since fixed). Everything else byte-identical to R12.
// ---------------------------------------------------------------------------

typedef unsigned short u16;
typedef short s16x8 __attribute__((ext_vector_type(8)));
typedef float f32x4 __attribute__((ext_vector_type(4)));

constexpr int BB  = 4;
constexpr int CH  = 1024;
constexpr int IN  = 256;
constexpr int ND  = 64;
constexpr int WH  = 4096;
constexpr int DCN = 128;
constexpr size_t TOT = (size_t)BB * CH * WH;

__device__ inline u16 f2bf(float f) {
  unsigned u = __float_as_uint(f);
  return (u16)((u + 0x7fffu + ((u >> 16) & 1u)) >> 16);
}
__device__ inline float bf2f(u16 u) { return __uint_as_float((unsigned)u << 16); }
__device__ inline s16x8 ld8(const u16* p) { return *(const s16x8*)p; }
#define MFMA16(a, b, c) __builtin_amdgcn_mfma_f32_16x16x32_bf16(a, b, c, 0, 0, 0)

// ---------------- init: Winb bf16, mu_t bf16 [b][n][c], piw, zero sp -------
__global__ void k_init(const float* __restrict__ Win, const float* __restrict__ mp,
                       const float* __restrict__ pi0, u16* __restrict__ Winb,
                       u16* __restrict__ mu_t, float* __restrict__ piw,
                       float* __restrict__ sp) {
  int idx = blockIdx.x * 256 + threadIdx.x;
  if (idx < IN * CH) { Winb[idx] = f2bf(Win[idx]); return; }
  int j = idx - IN * CH;
  if (j < BB * ND * IN) {
    int bb = j >> 14, n = (j >> 8) & 63, c = j & 255;
    mu_t[((size_t)(bb * ND + n)) * IN + c] = f2bf(mp[c * ND + n]);
    return;
  }
  j -= BB * ND * IN;
  if (j < BB * ND) { piw[j] = pi0[j & 63]; return; }
  j -= BB * ND;
  if (j < 3 * BB * ND) sp[j] = 0.f;
}

// ---------------- x1t = (W_in @ x + b_in)^T only (R12 exact) ---------------
__global__ __launch_bounds__(512) void k_x1(
    const float* __restrict__ x, const u16* __restrict__ Winb,
    const float* __restrict__ bin, u16* __restrict__ x1t) {
  __shared__ u16 lt[64][40];
  const int t = threadIdx.x, w = t >> 6, lr = t & 15, lg = (t >> 4) & 3;
  const int wc = w & 3, wm = w >> 2;
  const int m0 = blockIdx.x * 64, b = blockIdx.y;
  const int si = t >> 4, sm = (t & 15) * 4;
  const float* xb = x + (size_t)b * CH * WH + m0 + sm;
  f32x4 acc[4][2];
#pragma unroll
  for (int i = 0; i < 4; ++i)
#pragma unroll
    for (int j = 0; j < 2; ++j) acc[i][j] = (f32x4){0.f, 0.f, 0.f, 0.f};
  const u16* wp = Winb + (size_t)(wc * 64 + lr) * CH + lg * 8;

  float4 nxt = *(const float4*)&xb[(size_t)si * WH];
  for (int k0 = 0; k0 < CH; k0 += 32) {
    float4 cur = nxt;
    __syncthreads();
    lt[sm + 0][si] = f2bf(cur.x); lt[sm + 1][si] = f2bf(cur.y);
    lt[sm + 2][si] = f2bf(cur.z); lt[sm + 3][si] = f2bf(cur.w);
    if (k0 + 32 < CH) nxt = *(const float4*)&xb[(size_t)(k0 + 32 + si) * WH];
    __syncthreads();
    s16x8 af[4], bf[2];
#pragma unroll
    for (int i = 0; i < 4; ++i) af[i] = ld8(wp + (size_t)i * 16 * CH + k0);
#pragma unroll
    for (int j = 0; j < 2; ++j) bf[j] = *(const s16x8*)&lt[wm * 32 + j * 16 + lr][lg * 8];
#pragma unroll
    for (int i = 0; i < 4; ++i)
#pragma unroll
      for (int j = 0; j < 2; ++j) acc[i][j] = MFMA16(af[i], bf[j], acc[i][j]);
  }
#pragma unroll
  for (int i = 0; i < 4; ++i) {
    const int cb = wc * 64 + i * 16 + lg * 4;
    const float4 bi = *(const float4*)&bin[cb];
    const float bia[4] = {bi.x, bi.y, bi.z, bi.w};
#pragma unroll
    for (int j = 0; j < 2; ++j) {
      const int ml = wm * 32 + j * 16 + lr;
      float v[4];
#pragma unroll
      for (int r = 0; r < 4; ++r) v[r] = acc[i][j][r] + bia[r];
      ushort4 o;
      o.x = f2bf(v[0]); o.y = f2bf(v[1]); o.z = f2bf(v[2]); o.w = f2bf(v[3]);
      *(ushort4*)&x1t[((size_t)b * WH + m0 + ml) * IN + cb] = o;
    }
  }
}

// ---------------- fused EM iteration (R12 exact) ---------------------------
__global__ __launch_bounds__(256) void k_em(
    const u16* __restrict__ x1t, const u16* __restrict__ mu_t,
    const float* __restrict__ piw, float* __restrict__ sp,
    u16* __restrict__ pmn, u16* __restrict__ mup16, u16* __restrict__ gp16,
    int doLast) {
  __shared__ u16 xl[256][72];   // [c][m(64)+pad]
  __shared__ u16 ptl[64][72];   // [n][m(64)+pad]
  const int t = threadIdx.x, w = t >> 6, lr = t & 15, lg = (t >> 4) & 3;
  const int mch = blockIdx.x, b = blockIdx.y;
  // ---- phase A: lik + softmax (+ transpose staging) ----
  {
    f32x4 acc[4];
#pragma unroll
    for (int f = 0; f < 4; ++f) acc[f] = (f32x4){0.f, 0.f, 0.f, 0.f};
    const u16* ap = x1t + ((size_t)b * WH + mch * 64 + w * 16 + lr) * IN + lg * 8;
    const u16* bp = mu_t + ((size_t)b * ND + lr) * IN + lg * 8;
    const int ml = w * 16 + lr;
#pragma unroll
    for (int k0 = 0; k0 < IN; k0 += 32) {
      s16x8 av = ld8(ap + k0);
      const int cb = lg * 8 + k0;
#pragma unroll
      for (int e = 0; e < 8; ++e) xl[cb + e][ml] = (u16)av[e];
#pragma unroll
      for (int f = 0; f < 4; ++f)
        acc[f] = MFMA16(av, ld8(bp + f * 16 * IN + k0), acc[f]);
    }
    float pi_[4], spart[4] = {0.f, 0.f, 0.f, 0.f};
#pragma unroll
    for (int f = 0; f < 4; ++f) pi_[f] = piw[b * ND + f * 16 + lr];
#pragma unroll
    for (int r = 0; r < 4; ++r) {
      float v0 = acc[0][r], v1 = acc[1][r], v2 = acc[2][r], v3 = acc[3][r];
      float mx = fmaxf(fmaxf(v0, v1), fmaxf(v2, v3));
      mx = fmaxf(mx, __shfl_xor(mx, 1)); mx = fmaxf(mx, __shfl_xor(mx, 2));
      mx = fmaxf(mx, __shfl_xor(mx, 4)); mx = fmaxf(mx, __shfl_xor(mx, 8));
      float e0 = __expf(v0 - mx) * pi_[0], e1 = __expf(v1 - mx) * pi_[1];
      float e2 = __expf(v2 - mx) * pi_[2], e3 = __expf(v3 - mx) * pi_[3];
      float s = e0 + e1 + e2 + e3;
      s += __shfl_xor(s, 1); s += __shfl_xor(s, 2);
      s += __shfl_xor(s, 4); s += __shfl_xor(s, 8);
      const float inv = 1.f / (1e-18f + s);
      e0 *= inv; e1 *= inv; e2 *= inv; e3 *= inv;
      const int mloc = w * 16 + lg * 4 + r;
      u16 q0 = f2bf(e0), q1 = f2bf(e1), q2 = f2bf(e2), q3 = f2bf(e3);
      ptl[0 + lr][mloc]  = q0; ptl[16 + lr][mloc] = q1;
      ptl[32 + lr][mloc] = q2; ptl[48 + lr][mloc] = q3;
      if (doLast) {
        const size_t gbase = ((size_t)b * WH + mch * 64 + mloc) * ND + lr;
        pmn[gbase + 0]  = q0; pmn[gbase + 16] = q1;
        pmn[gbase + 32] = q2; pmn[gbase + 48] = q3;
      }
      spart[0] += e0; spart[1] += e1; spart[2] += e2; spart[3] += e3;
    }
#pragma unroll
    for (int f = 0; f < 4; ++f) {
      spart[f] += __shfl_xor(spart[f], 16);
      spart[f] += __shfl_xor(spart[f], 32);
    }
    if (((t >> 4) & 3) == 0) {
#pragma unroll
      for (int f = 0; f < 4; ++f)
        atomicAdd(&sp[b * ND + f * 16 + lr], spart[f]);
    }
  }
  __syncthreads();
  // ---- phase B: mu partials from LDS (bf16 out) ----
  {
    f32x4 acc[4][4];
#pragma unroll
    for (int i = 0; i < 4; ++i)
#pragma unroll
      for (int j = 0; j < 4; ++j) acc[i][j] = (f32x4){0.f, 0.f, 0.f, 0.f};
#pragma unroll
    for (int ks = 0; ks < 2; ++ks) {
      s16x8 af[4], bf[4];
#pragma unroll
      for (int i = 0; i < 4; ++i)
        af[i] = *(const s16x8*)&xl[w * 64 + i * 16 + lr][ks * 32 + lg * 8];
#pragma unroll
      for (int j = 0; j < 4; ++j)
        bf[j] = *(const s16x8*)&ptl[j * 16 + lr][ks * 32 + lg * 8];
#pragma unroll
      for (int i = 0; i < 4; ++i)
#pragma unroll
        for (int j = 0; j < 4; ++j) acc[i][j] = MFMA16(af[i], bf[j], acc[i][j]);
    }
    u16* mo = mup16 + ((size_t)mch * BB + b) * (IN * ND);
#pragma unroll
    for (int i = 0; i < 4; ++i)
#pragma unroll
      for (int j = 0; j < 4; ++j)
#pragma unroll
        for (int r = 0; r < 4; ++r) {
          const int c = w * 64 + i * 16 + lg * 4 + r, n = j * 16 + lr;
          mo[c * ND + n] = f2bf(acc[i][j][r]);
        }
  }
  // ---- phase C: G partials (last iter, bf16 out) ----
  if (doLast) {
    f32x4 acc[4];
#pragma unroll
    for (int j = 0; j < 4; ++j) acc[j] = (f32x4){0.f, 0.f, 0.f, 0.f};
#pragma unroll
    for (int ks = 0; ks < 2; ++ks) {
      s16x8 av = *(const s16x8*)&ptl[w * 16 + lr][ks * 32 + lg * 8];
#pragma unroll
      for (int j = 0; j < 4; ++j) {
        s16x8 bq = *(const s16x8*)&ptl[j * 16 + lr][ks * 32 + lg * 8];
        acc[j] = MFMA16(av, bq, acc[j]);
      }
    }
    u16* go = gp16 + ((size_t)mch * BB + b) * (ND * ND);
#pragma unroll
    for (int j = 0; j < 4; ++j)
#pragma unroll
      for (int r = 0; r < 4; ++r) {
        const int n1 = w * 16 + lg * 4 + r, n2 = j * 16 + lr;
        go[n1 * ND + n2] = f2bf(acc[j][r]);
      }
  }
}

// ---------------- mu reduce + normalize + piw (+ G reduce last iter) -------
__global__ void k_mu_red(const u16* __restrict__ mup16, const float* __restrict__ spb,
                         float* __restrict__ piw, float* __restrict__ mu,
                         u16* __restrict__ mu_t, const u16* __restrict__ gp16,
                         float* __restrict__ G, int doG) {
  const int idx = blockIdx.x * 256 + threadIdx.x;   // grid 256 -> 65536
  const int bb = idx >> 14, c = (idx >> 6) & 255, n = idx & 63;
  float s = 0.f;
#pragma unroll 8
  for (int ch = 0; ch < 64; ++ch)
    s += bf2f(mup16[((size_t)ch * BB + bb) * (IN * ND) + (idx & 16383)]);
  const float v = s / (1e-18f + spb[bb * ND + n]);
  mu[idx] = v;
  mu_t[((size_t)(bb * ND + n)) * IN + c] = f2bf(v);
  if (idx < BB * ND) piw[idx] = spb[idx] * (1.f / (float)WH);
  if (doG && idx < BB * ND * ND) {
    float g = 0.f;
#pragma unroll 8
    for (int ch = 0; ch < 64; ++ch)
      g += bf2f(gp16[(size_t)ch * (BB * ND * ND) + idx]);
    G[idx] = g;
  }
}

// ---------------- z-GEMM body: z = W @ v (f32) + zb bf16 -------------------
__device__ void zg_body(const float* __restrict__ W, const float* __restrict__ v,
                        float* __restrict__ z, u16* __restrict__ zb,
                        int o0, int bb, int t, char* smem) {
  float (*As)[68] = (float(*)[68])smem;
  float (*Bs)[64] = (float(*)[64])(smem + 4352);
  const int tx = t & 15, ty = t >> 4;
  const int aoo = t >> 2, akq = (t & 3) * 4;
  const int bkk = t >> 4, bnq = (t & 15) * 4;
  float acc[4][4] = {};
  for (int k0 = 0; k0 < IN; k0 += 16) {
    {
      float4 w4 = *(const float4*)&W[(size_t)(o0 + aoo) * IN + k0 + akq];
      As[akq + 0][aoo] = w4.x; As[akq + 1][aoo] = w4.y;
      As[akq + 2][aoo] = w4.z; As[akq + 3][aoo] = w4.w;
    }
    *(float4*)&Bs[bkk][bnq] = *(const float4*)&v[((size_t)bb * IN + k0 + bkk) * ND + bnq];
    __syncthreads();
#pragma unroll
    for (int kk = 0; kk < 16; ++kk) {
      float4 a4 = *(const float4*)&As[kk][ty * 4];
      float4 b4 = *(const float4*)&Bs[kk][tx * 4];
      float ar[4] = {a4.x, a4.y, a4.z, a4.w}, br[4] = {b4.x, b4.y, b4.z, b4.w};
#pragma unroll
      for (int i = 0; i < 4; ++i)
#pragma unroll
        for (int j = 0; j < 4; ++j) acc[i][j] += ar[i] * br[j];
    }
    __syncthreads();
  }
#pragma unroll
  for (int i = 0; i < 4; ++i) {
    float4 r = make_float4(acc[i][0], acc[i][1], acc[i][2], acc[i][3]);
    const size_t off = ((size_t)bb * CH + o0 + ty * 4 + i) * ND + tx * 4;
    *(float4*)&z[off] = r;
    ushort4 h;
    h.x = f2bf(r.x); h.y = f2bf(r.y); h.z = f2bf(r.z); h.w = f2bf(r.w);
    *(ushort4*)&zb[off] = h;
  }
}

// ---------------- gcA (bid 0-27) || z2-GEMM (bid 32-95) --------------------
__global__ __launch_bounds__(256) void k_gcAz2(
    const float* __restrict__ mu, const float* __restrict__ gw,
    const float* __restrict__ Wa, const float* __restrict__ ba,
    const float* __restrict__ Wd, const float* __restrict__ bd,
    float* __restrict__ qbuf, float* __restrict__ xabuf, float* __restrict__ dv,
    const float* __restrict__ Wo2, float* __restrict__ z2, u16* __restrict__ zb2) {
  __shared__ __align__(16) char smem[66560];
  const int t = threadIdx.x, bid = blockIdx.x;
  if (bid < 28) {
    const int blk = bid % 7, b = bid / 7;
    float* sx2 = (float*)smem;
    float* srm = (float*)(smem + 65536);
    if (blk < 6) {
      const float* src = mu + (size_t)b * IN * ND;
#pragma unroll
      for (int q4 = 0; q4 < 16; ++q4)
        *(float4*)&sx2[q4 * 1024 + t * 4] = *(const float4*)&src[q4 * 1024 + t * 4];
      __syncthreads();
      const int rg = t >> 4, cg = t & 15;
      const float* W = (blk < 4) ? gw + (size_t)(blk * 64 + rg * 4) * IN
                                 : Wa + (size_t)((blk - 4) * 64 + rg * 4) * IN;
      float acc[4][4] = {};
      for (int i4 = 0; i4 < 64; ++i4) {
        float4 xv[4];
#pragma unroll
        for (int e = 0; e < 4; ++e)
          xv[e] = *(const float4*)&sx2[(i4 * 4 + e) * 64 + cg * 4];
#pragma unroll
        for (int rr = 0; rr < 4; ++rr) {
          const float4 w4 = *(const float4*)&W[(size_t)rr * IN + i4 * 4];
          acc[rr][0] += w4.x * xv[0].x + w4.y * xv[1].x + w4.z * xv[2].x + w4.w * xv[3].x;
          acc[rr][1] += w4.x * xv[0].y + w4.y * xv[1].y + w4.z * xv[2].y + w4.w * xv[3].y;
          acc[rr][2] += w4.x * xv[0].z + w4.y * xv[1].z + w4.z * xv[2].z + w4.w * xv[3].z;
          acc[rr][3] += w4.x * xv[0].w + w4.y * xv[1].w + w4.z * xv[2].w + w4.w * xv[3].w;
        }
      }
      if (blk < 4) {
        float* dst = qbuf + (size_t)b * IN * ND + (size_t)(blk * 64 + rg * 4) * ND + cg * 4;
#pragma unroll
        for (int rr = 0; rr < 4; ++rr)
          *(float4*)&dst[(size_t)rr * ND] =
              make_float4(acc[rr][0], acc[rr][1], acc[rr][2], acc[rr][3]);
      } else {
        const int xr = (blk - 4) * 64 + rg * 4;
        float* dst = xabuf + (size_t)b * DCN * ND + (size_t)xr * ND + cg * 4;
#pragma unroll
        for (int rr = 0; rr < 4; ++rr) {
          const float bv = ba[xr + rr];
          *(float4*)&dst[(size_t)rr * ND] =
              make_float4(acc[rr][0] + bv, acc[rr][1] + bv, acc[rr][2] + bv, acc[rr][3] + bv);
        }
      }
    } else {
      {
        const float* row = mu + (size_t)b * IN * ND + (size_t)t * ND;
        float s = 0.f;
#pragma unroll
        for (int n4 = 0; n4 < 16; ++n4) {
          float4 v = *(const float4*)&row[n4 * 4];
          s += v.x + v.y + v.z + v.w;
        }
        srm[t] = s * (1.f / ND);
      }
      __syncthreads();
      if (t < DCN) {
        float a = 0.f;
#pragma unroll
        for (int i4 = 0; i4 < 64; ++i4) {
          float4 w4 = *(const float4*)&Wd[(size_t)t * IN + i4 * 4];
          float4 r4 = *(const float4*)&srm[i4 * 4];
          a += w4.x * r4.x + w4.y * r4.y + w4.z * r4.z + w4.w * r4.w;
        }
        a += bd[t];
        dv[b * DCN + t] = 1.f / (1.f + __expf(-a)) - 0.5f;
      }
    }
  } else if (bid >= 32 && bid < 96) {
    const int zid = bid - 32;
    zg_body(Wo2, mu, z2, zb2, (zid & 15) * 64, zid >> 4, t, smem);
  }
}

// ---------------- GC-B + GC-C fused (R12 exact) ----------------------------
__global__ __launch_bounds__(256) void k_gcBC(
    const float* __restrict__ xabuf, const float* __restrict__ dv,
    const float* __restrict__ qbuf, const float* __restrict__ mu,
    float* __restrict__ x2g) {
  __shared__ float sxa[DCN * ND];
  __shared__ float sA[ND * 65];
  __shared__ float sq[64 * 68];
  __shared__ float sdv[DCN];
  __shared__ float su[ND];
  __shared__ float sdeg[ND];
  const int t = threadIdx.x, qtr = blockIdx.x, b = blockIdx.y;
  {
    const float* src = xabuf + (size_t)b * DCN * ND;
#pragma unroll
    for (int q4 = 0; q4 < 8; ++q4)
      *(float4*)&sxa[q4 * 1024 + t * 4] = *(const float4*)&src[q4 * 1024 + t * 4];
    if (t < DCN) sdv[t] = dv[b * DCN + t];
    const int r = t >> 2, seg = (t & 3) * 16;
    const float* qs = qbuf + (size_t)b * IN * ND + (size_t)(qtr * 64 + r) * ND + seg;
#pragma unroll
    for (int f = 0; f < 4; ++f) {
      float4 v = *(const float4*)&qs[f * 4];
      sq[r * 68 + seg + f * 4 + 0] = v.x; sq[r * 68 + seg + f * 4 + 1] = v.y;
      sq[r * 68 + seg + f * 4 + 2] = v.z; sq[r * 68 + seg + f * 4 + 3] = v.w;
    }
  }
  __syncthreads();
  if (t < ND) {
    float s = 0.f;
    for (int dc = 0; dc < DCN; ++dc) s += sxa[dc * ND + t];
    su[t] = s;
  }
  __syncthreads();
  {
    const int n1g = t >> 4, n2g = t & 15;
    float acc[4][4] = {};
    for (int dc = 0; dc < DCN; ++dc) {
      const float dvv = sdv[dc];
      float4 v1 = *(const float4*)&sxa[dc * ND + n1g * 4];
      const float4 v2 = *(const float4*)&sxa[dc * ND + n2g * 4];
      v1.x *= dvv; v1.y *= dvv; v1.z *= dvv; v1.w *= dvv;
      acc[0][0] += v1.x * v2.x; acc[0][1] += v1.x * v2.y;
      acc[0][2] += v1.x * v2.z; acc[0][3] += v1.x * v2.w;
      acc[1][0] += v1.y * v2.x; acc[1][1] += v1.y * v2.y;
      acc[1][2] += v1.y * v2.z; acc[1][3] += v1.y * v2.w;
      acc[2][0] += v1.z * v2.x; acc[2][1] += v1.z * v2.y;
      acc[2][2] += v1.z * v2.z; acc[2][3] += v1.z * v2.w;
      acc[3][0] += v1.w * v2.x; acc[3][1] += v1.w * v2.y;
      acc[3][2] += v1.w * v2.z; acc[3][3] += v1.w * v2.w;
    }
#pragma unroll
    for (int i = 0; i < 4; ++i) {
      const int n1 = n1g * 4 + i;
      const float u1 = su[n1];
#pragma unroll
      for (int j = 0; j < 4; ++j) {
        const int n2 = n2g * 4 + j;
        const float v = acc[i][j] + 0.5f * u1 * su[n2];
        sA[n1 * 65 + n2] = fmaxf(v, 0.f) + (n1 == n2 ? 1.f : 0.f);
      }
    }
  }
  __syncthreads();
  if (t < ND) {
    float s = 0.f;
    for (int m = 0; m < ND; ++m) s += sA[m * 65 + t];
    sdeg[t] = rsqrtf(s);
  }
  __syncthreads();
  {
    const int n1g = t >> 4, n2g = t & 15;
#pragma unroll
    for (int i = 0; i < 4; ++i) {
      const int n1 = n1g * 4 + i;
      const float dr = sdeg[n1];
#pragma unroll
      for (int e = 0; e < 4; ++e)
        sA[n1 * 65 + n2g * 4 + e] *= dr * sdeg[n2g * 4 + e];
    }
  }
  __syncthreads();
  {
    const int rg = t >> 4, cg2 = t & 15;
    float acc[4][4] = {};
    for (int k = 0; k < ND; ++k) {
      const float4 a4 = *(const float4*)&sA[k * 65 + cg2 * 4];
      float qv[4];
#pragma unroll
      for (int rr = 0; rr < 4; ++rr) qv[rr] = sq[(rg * 4 + rr) * 68 + k];
#pragma unroll
      for (int rr = 0; rr < 4; ++rr) {
        acc[rr][0] += qv[rr] * a4.x; acc[rr][1] += qv[rr] * a4.y;
        acc[rr][2] += qv[rr] * a4.z; acc[rr][3] += qv[rr] * a4.w;
      }
    }
#pragma unroll
    for (int rr = 0; rr < 4; ++rr) {
      const size_t off = (size_t)b * IN * ND + (size_t)(qtr * 64 + rg * 4 + rr) * ND + cg2 * 4;
      const float4 xv = *(const float4*)&mu[off];
      float4 o;
      o.x = fmaxf(acc[rr][0], 0.f) + xv.x; o.y = fmaxf(acc[rr][1], 0.f) + xv.y;
      o.z = fmaxf(acc[rr][2], 0.f) + xv.z; o.w = fmaxf(acc[rr][3], 0.f) + xv.w;
      *(float4*)&x2g[off] = o;
    }
  }
}

// ---------------- z1-GEMM standalone ---------------------------------------
__global__ __launch_bounds__(256) void k_zg(
    const float* __restrict__ W, const float* __restrict__ v,
    float* __restrict__ z, u16* __restrict__ zb) {
  __shared__ __align__(16) char smem[8448];
  zg_body(W, v, z, zb, blockIdx.x * 64, blockIdx.y, threadIdx.x, smem);
}

// ---------------- BN stats (R12 exact) -------------------------------------
__global__ __launch_bounds__(256) void k_stats(
    const float* __restrict__ z1, const float* __restrict__ z2,
    const float* __restrict__ sp, const float* __restrict__ G,
    const float* __restrict__ gam, const float* __restrict__ bet,
    const float* __restrict__ gam2, const float* __restrict__ bet2,
    float* __restrict__ abc) {
  const int t = threadIdx.x;
  const int o = blockIdx.x * 4 + (t >> 6), lane = t & 63;
#pragma unroll
  for (int br = 0; br < 2; ++br) {
    const float* z = br ? z2 : z1;
    float macc = 0.f, eacc = 0.f;
    for (int bb = 0; bb < BB; ++bb) {
      const float zv = z[((size_t)bb * CH + o) * ND + lane];
      float s1 = zv * sp[bb * ND + lane];
      const float* Gb = G + (size_t)bb * ND * ND;
      float gz = 0.f;
      for (int k = 0; k < ND; ++k) {
        const float zk = __shfl(zv, k);
        gz += Gb[k * ND + lane] * zk;
      }
      float q = zv * gz;
#pragma unroll
      for (int off = 32; off; off >>= 1) {
        s1 += __shfl_xor(s1, off);
        q  += __shfl_xor(q, off);
      }
      macc += s1; eacc += q;
    }
    const float inv = 1.f / (float)((size_t)BB * WH);
    const float mean = macc * inv;
    const float var  = eacc * inv - mean * mean;
    const float a = (br ? gam2[o] : gam[o]) * rsqrtf(var + 1e-5f);
    const float c = (br ? bet2[o] : bet[o]) - mean * a;
    if (lane == 0) { abc[br * 2 * CH + o] = a; abc[br * 2 * CH + CH + o] = c; }
  }
}

// ---------------- epilogue: MFMA y=z.post^T, BN, residual relus (plain) ----
__global__ __launch_bounds__(256) void k_epi(
    const u16* __restrict__ zb1, const u16* __restrict__ zb2,
    const u16* __restrict__ post, const float* __restrict__ abc,
    const float* __restrict__ x, float* __restrict__ out1, float* __restrict__ out2) {
  const int t = threadIdx.x, w = t >> 6, lr = t & 15, lg = (t >> 4) & 3;
  const int m0 = blockIdx.x * 256 + w * 64, o0 = blockIdx.y * 64, bb = blockIdx.z;
  f32x4 acc1[4][4], acc2[4][4];
#pragma unroll
  for (int i = 0; i < 4; ++i)
#pragma unroll
    for (int j = 0; j < 4; ++j) {
      acc1[i][j] = (f32x4){0.f, 0.f, 0.f, 0.f};
      acc2[i][j] = (f32x4){0.f, 0.f, 0.f, 0.f};
    }
  const u16* z1p = zb1 + ((size_t)bb * CH + o0 + lr) * ND + lg * 8;
  const u16* z2p = zb2 + ((size_t)bb * CH + o0 + lr) * ND + lg * 8;
  const u16* pp  = post + ((size_t)bb * WH + m0 + lr) * ND + lg * 8;
#pragma unroll
  for (int ks = 0; ks < 2; ++ks) {
    s16x8 a1[4], a2[4], bq[4];
#pragma unroll
    for (int i = 0; i < 4; ++i) {
      a1[i] = ld8(z1p + i * 16 * ND + ks * 32);
      a2[i] = ld8(z2p + i * 16 * ND + ks * 32);
    }
#pragma unroll
    for (int j = 0; j < 4; ++j) bq[j] = ld8(pp + j * 16 * ND + ks * 32);
#pragma unroll
    for (int i = 0; i < 4; ++i)
#pragma unroll
      for (int j = 0; j < 4; ++j) {
        acc1[i][j] = MFMA16(a1[i], bq[j], acc1[i][j]);
        acc2[i][j] = MFMA16(a2[i], bq[j], acc2[i][j]);
      }
  }
#pragma unroll
  for (int i = 0; i < 4; ++i)
#pragma unroll
    for (int r = 0; r < 4; ++r) {
      const int o = o0 + i * 16 + lg * 4 + r;
      const float a1v = abc[o], c1v = abc[CH + o];
      const float a2v = abc[2 * CH + o], c2v = abc[3 * CH + o];
      const size_t base = ((size_t)bb * CH + o) * WH + m0 + lr;
#pragma unroll
      for (int j = 0; j < 4; ++j) {
        const size_t off = base + j * 16;
        const float xv = x[off];
        out1[off] = fmaxf(fmaxf(a1v * acc1[i][j][r] + c1v, 0.f) + xv, 0.f);
        out2[off] = fmaxf(fmaxf(a2v * acc2[i][j][r] + c2v, 0.f) + xv, 0.f);
      }
    }
}

// ---------------------------------------------------------------------------
extern "C" void kernel_launch(void* const* d_in, const int* in_sizes, int n_in,
                              void* d_out, int out_size, void* d_ws, size_t ws_size,
                              hipStream_t stream) {
  (void)in_sizes; (void)n_in; (void)out_size; (void)ws_size;
  const float* x    = (const float*)d_in[0];
  const float* Win  = (const float*)d_in[1];
  const float* bin  = (const float*)d_in[2];
  const float* mp   = (const float*)d_in[3];
  const float* pi0  = (const float*)d_in[4];
  const float* Wa   = (const float*)d_in[5];
  const float* ba   = (const float*)d_in[6];
  const float* Wd   = (const float*)d_in[7];
  const float* bd   = (const float*)d_in[8];
  const float* gw   = (const float*)d_in[9];
  const float* Wo   = (const float*)d_in[10];
  const float* gam  = (const float*)d_in[12];
  const float* bet  = (const float*)d_in[13];
  const float* Wo2  = (const float*)d_in[14];
  const float* gam2 = (const float*)d_in[16];
  const float* bet2 = (const float*)d_in[17];

  char* ob = (char*)d_out;
  char* wp = (char*)d_ws;
  // scratch in d_out (dead before k_epi writes outputs):
  u16*   mup16 = (u16*)(ob + 0);          // 8.4 MB (64 chunks, bf16)
  u16*   gp16  = (u16*)(ob + 8388608);    // 2 MB (bf16)
  float* z1    = (float*)(ob + 10485760); // 1 MB
  float* z2    = (float*)(ob + 11534336); // 1 MB
  // ws (~21.7 MB):
  u16*   x1t   = (u16*)(wp + 8388608);     // 8.4 MB [b][m][c]
  u16*   Winb  = (u16*)(wp + 16777216);    // 0.5 MB
  u16*   mu_t  = (u16*)(wp + 17301504);    // 128 KB [b][n][c]
  u16*   pmn   = (u16*)(wp + 17432576);    // 2 MB [b][m][n]
  float* mu    = (float*)(wp + 19529728);  // 256 KB [b][c][n]
  float* x2g   = (float*)(wp + 19791872);  // 256 KB
  u16*   zb1   = (u16*)(wp + 20054016);    // 0.5 MB
  u16*   zb2   = (u16*)(wp + 20578304);    // 0.5 MB
  float* sp3   = (float*)(wp + 21102592);  // 3 KB
  float* piw   = (float*)(wp + 21105664);  // 1 KB
  float* abc   = (float*)(wp + 21106688);  // 16 KB
  float* G     = (float*)(wp + 21123072);  // 64 KB
  float* qbuf  = (float*)(wp + 21188608);  // 256 KB
  float* xabuf = (float*)(wp + 21450752);  // 128 KB
  float* dvb   = (float*)(wp + 21581824);  // 2 KB
  float* out1  = (float*)d_out;
  float* out2  = out1 + TOT;

  k_init<<<dim3(1284), 256, 0, stream>>>(Win, mp, pi0, Winb, mu_t, piw, sp3);
  k_x1<<<dim3(64, BB), 512, 0, stream>>>(x, Winb, bin, x1t);
  for (int it = 0; it < 3; ++it) {
    float* spb = sp3 + it * 256;
    const int doLast = (it == 2);
    k_em<<<dim3(64, BB), 256, 0, stream>>>(x1t, mu_t, piw, spb, pmn,
                                           mup16, gp16, doLast);
    k_mu_red<<<dim3(256), 256, 0, stream>>>(mup16, spb, piw, mu, mu_t,
                                            gp16, G, doLast);
  }
  k_gcAz2<<<dim3(96), 256, 0, stream>>>(mu, gw, Wa, ba, Wd, bd, qbuf, xabuf, dvb,
                                        Wo2, z2, zb2);
  k_gcBC<<<dim3(4, BB), 256, 0, stream>>>(xabuf, dvb, qbuf, mu, x2g);
  k_zg<<<dim3(16, BB), 256, 0, stream>>>(Wo, x2g, z1, zb1);
  k_stats<<<dim3(256), 256, 0, stream>>>(z1, z2, sp3 + 512, G, gam, bet, gam2, bet2, abc);
  k_epi<<<dim3(16, 16, BB), 256, 0, stream>>>(zb1, zb2, pmn, abc, x, out1, out2);
}

// Round 14
// 223.700 us; speedup vs baseline: 1.0737x; 1.0737x over previous
//
#include <hip/hip_runtime.h>
#include <math.h>

// ---------------------------------------------------------------------------
// Intra_graph forward, MI355X. Round 14: REVERT to R12 (best, 224.3us).
// R13's gcAz2 merge falsified (+16us): the 66.5KB static LDS union taxes all
// 96 blocks including the 64 z2 blocks that need only 8.5KB. Lesson: don't
// union LDS footprints across heterogeneous block roles.
// This source is R12 byte-for-byte.
// ---------------------------------------------------------------------------

typedef unsigned short u16;
typedef short s16x8 __attribute__((ext_vector_type(8)));
typedef float f32x4 __attribute__((ext_vector_type(4)));

constexpr int BB  = 4;
constexpr int CH  = 1024;
constexpr int IN  = 256;
constexpr int ND  = 64;
constexpr int WH  = 4096;
constexpr int DCN = 128;
constexpr size_t TOT = (size_t)BB * CH * WH;

__device__ inline u16 f2bf(float f) {
  unsigned u = __float_as_uint(f);
  return (u16)((u + 0x7fffu + ((u >> 16) & 1u)) >> 16);
}
__device__ inline float bf2f(u16 u) { return __uint_as_float((unsigned)u << 16); }
__device__ inline s16x8 ld8(const u16* p) { return *(const s16x8*)p; }
#define MFMA16(a, b, c) __builtin_amdgcn_mfma_f32_16x16x32_bf16(a, b, c, 0, 0, 0)

// ---------------- init: Winb bf16, mu_t bf16 [b][n][c], piw, zero sp -------
__global__ void k_init(const float* __restrict__ Win, const float* __restrict__ mp,
                       const float* __restrict__ pi0, u16* __restrict__ Winb,
                       u16* __restrict__ mu_t, float* __restrict__ piw,
                       float* __restrict__ sp) {
  int idx = blockIdx.x * 256 + threadIdx.x;
  if (idx < IN * CH) { Winb[idx] = f2bf(Win[idx]); return; }
  int j = idx - IN * CH;
  if (j < BB * ND * IN) {
    int bb = j >> 14, n = (j >> 8) & 63, c = j & 255;
    mu_t[((size_t)(bb * ND + n)) * IN + c] = f2bf(mp[c * ND + n]);
    return;
  }
  j -= BB * ND * IN;
  if (j < BB * ND) { piw[j] = pi0[j & 63]; return; }
  j -= BB * ND;
  if (j < 3 * BB * ND) sp[j] = 0.f;
}

// ---------------- x1t = (W_in @ x + b_in)^T only ---------------------------
// grid (64 m-tiles, BB), 512 threads = 8 waves. Wave: c-tile 64 x m-half 32.
__global__ __launch_bounds__(512) void k_x1(
    const float* __restrict__ x, const u16* __restrict__ Winb,
    const float* __restrict__ bin, u16* __restrict__ x1t) {
  __shared__ u16 lt[64][40];
  const int t = threadIdx.x, w = t >> 6, lr = t & 15, lg = (t >> 4) & 3;
  const int wc = w & 3, wm = w >> 2;
  const int m0 = blockIdx.x * 64, b = blockIdx.y;
  const int si = t >> 4, sm = (t & 15) * 4;
  const float* xb = x + (size_t)b * CH * WH + m0 + sm;
  f32x4 acc[4][2];
#pragma unroll
  for (int i = 0; i < 4; ++i)
#pragma unroll
    for (int j = 0; j < 2; ++j) acc[i][j] = (f32x4){0.f, 0.f, 0.f, 0.f};
  const u16* wp = Winb + (size_t)(wc * 64 + lr) * CH + lg * 8;

  float4 nxt = *(const float4*)&xb[(size_t)si * WH];
  for (int k0 = 0; k0 < CH; k0 += 32) {
    float4 cur = nxt;
    __syncthreads();
    lt[sm + 0][si] = f2bf(cur.x); lt[sm + 1][si] = f2bf(cur.y);
    lt[sm + 2][si] = f2bf(cur.z); lt[sm + 3][si] = f2bf(cur.w);
    if (k0 + 32 < CH) nxt = *(const float4*)&xb[(size_t)(k0 + 32 + si) * WH];
    __syncthreads();
    s16x8 af[4], bf[2];
#pragma unroll
    for (int i = 0; i < 4; ++i) af[i] = ld8(wp + (size_t)i * 16 * CH + k0);
#pragma unroll
    for (int j = 0; j < 2; ++j) bf[j] = *(const s16x8*)&lt[wm * 32 + j * 16 + lr][lg * 8];
#pragma unroll
    for (int i = 0; i < 4; ++i)
#pragma unroll
      for (int j = 0; j < 2; ++j) acc[i][j] = MFMA16(af[i], bf[j], acc[i][j]);
  }
#pragma unroll
  for (int i = 0; i < 4; ++i) {
    const int cb = wc * 64 + i * 16 + lg * 4;
    const float4 bi = *(const float4*)&bin[cb];
    const float bia[4] = {bi.x, bi.y, bi.z, bi.w};
#pragma unroll
    for (int j = 0; j < 2; ++j) {
      const int ml = wm * 32 + j * 16 + lr;      // local m in [0,64)
      float v[4];
#pragma unroll
      for (int r = 0; r < 4; ++r) v[r] = acc[i][j][r] + bia[r];
      ushort4 o;
      o.x = f2bf(v[0]); o.y = f2bf(v[1]); o.z = f2bf(v[2]); o.w = f2bf(v[3]);
      *(ushort4*)&x1t[((size_t)b * WH + m0 + ml) * IN + cb] = o;
    }
  }
}

// ---------------- fused EM iteration (LDS-transposed x1 tile) --------------
// grid (64 m-chunks of 64, BB), 256 threads = 4 waves.
__global__ __launch_bounds__(256) void k_em(
    const u16* __restrict__ x1t, const u16* __restrict__ mu_t,
    const float* __restrict__ piw, float* __restrict__ sp,
    u16* __restrict__ pmn, u16* __restrict__ mup16, u16* __restrict__ gp16,
    int doLast) {
  __shared__ u16 xl[256][72];   // [c][m(64)+pad] 144B rows (16B aligned)
  __shared__ u16 ptl[64][72];   // [n][m(64)+pad]
  const int t = threadIdx.x, w = t >> 6, lr = t & 15, lg = (t >> 4) & 3;
  const int mch = blockIdx.x, b = blockIdx.y;
  // ---- phase A: lik + softmax (+ transpose staging) ----
  {
    f32x4 acc[4];
#pragma unroll
    for (int f = 0; f < 4; ++f) acc[f] = (f32x4){0.f, 0.f, 0.f, 0.f};
    const u16* ap = x1t + ((size_t)b * WH + mch * 64 + w * 16 + lr) * IN + lg * 8;
    const u16* bp = mu_t + ((size_t)b * ND + lr) * IN + lg * 8;
    const int ml = w * 16 + lr;
#pragma unroll
    for (int k0 = 0; k0 < IN; k0 += 32) {
      s16x8 av = ld8(ap + k0);
      const int cb = lg * 8 + k0;
#pragma unroll
      for (int e = 0; e < 8; ++e) xl[cb + e][ml] = (u16)av[e];
#pragma unroll
      for (int f = 0; f < 4; ++f)
        acc[f] = MFMA16(av, ld8(bp + f * 16 * IN + k0), acc[f]);
    }
    float pi_[4], spart[4] = {0.f, 0.f, 0.f, 0.f};
#pragma unroll
    for (int f = 0; f < 4; ++f) pi_[f] = piw[b * ND + f * 16 + lr];
#pragma unroll
    for (int r = 0; r < 4; ++r) {
      float v0 = acc[0][r], v1 = acc[1][r], v2 = acc[2][r], v3 = acc[3][r];
      float mx = fmaxf(fmaxf(v0, v1), fmaxf(v2, v3));
      mx = fmaxf(mx, __shfl_xor(mx, 1)); mx = fmaxf(mx, __shfl_xor(mx, 2));
      mx = fmaxf(mx, __shfl_xor(mx, 4)); mx = fmaxf(mx, __shfl_xor(mx, 8));
      float e0 = __expf(v0 - mx) * pi_[0], e1 = __expf(v1 - mx) * pi_[1];
      float e2 = __expf(v2 - mx) * pi_[2], e3 = __expf(v3 - mx) * pi_[3];
      float s = e0 + e1 + e2 + e3;
      s += __shfl_xor(s, 1); s += __shfl_xor(s, 2);
      s += __shfl_xor(s, 4); s += __shfl_xor(s, 8);
      const float inv = 1.f / (1e-18f + s);
      e0 *= inv; e1 *= inv; e2 *= inv; e3 *= inv;
      const int mloc = w * 16 + lg * 4 + r;
      u16 q0 = f2bf(e0), q1 = f2bf(e1), q2 = f2bf(e2), q3 = f2bf(e3);
      ptl[0 + lr][mloc]  = q0; ptl[16 + lr][mloc] = q1;
      ptl[32 + lr][mloc] = q2; ptl[48 + lr][mloc] = q3;
      if (doLast) {
        const size_t gbase = ((size_t)b * WH + mch * 64 + mloc) * ND + lr;
        pmn[gbase + 0]  = q0; pmn[gbase + 16] = q1;
        pmn[gbase + 32] = q2; pmn[gbase + 48] = q3;
      }
      spart[0] += e0; spart[1] += e1; spart[2] += e2; spart[3] += e3;
    }
#pragma unroll
    for (int f = 0; f < 4; ++f) {
      spart[f] += __shfl_xor(spart[f], 16);
      spart[f] += __shfl_xor(spart[f], 32);
    }
    if (((t >> 4) & 3) == 0) {
#pragma unroll
      for (int f = 0; f < 4; ++f)
        atomicAdd(&sp[b * ND + f * 16 + lr], spart[f]);
    }
  }
  __syncthreads();
  // ---- phase B: mu partials from LDS (bf16 out) ----
  {
    f32x4 acc[4][4];
#pragma unroll
    for (int i = 0; i < 4; ++i)
#pragma unroll
      for (int j = 0; j < 4; ++j) acc[i][j] = (f32x4){0.f, 0.f, 0.f, 0.f};
#pragma unroll
    for (int ks = 0; ks < 2; ++ks) {
      s16x8 af[4], bf[4];
#pragma unroll
      for (int i = 0; i < 4; ++i)
        af[i] = *(const s16x8*)&xl[w * 64 + i * 16 + lr][ks * 32 + lg * 8];
#pragma unroll
      for (int j = 0; j < 4; ++j)
        bf[j] = *(const s16x8*)&ptl[j * 16 + lr][ks * 32 + lg * 8];
#pragma unroll
      for (int i = 0; i < 4; ++i)
#pragma unroll
        for (int j = 0; j < 4; ++j) acc[i][j] = MFMA16(af[i], bf[j], acc[i][j]);
    }
    u16* mo = mup16 + ((size_t)mch * BB + b) * (IN * ND);
#pragma unroll
    for (int i = 0; i < 4; ++i)
#pragma unroll
      for (int j = 0; j < 4; ++j)
#pragma unroll
        for (int r = 0; r < 4; ++r) {
          const int c = w * 64 + i * 16 + lg * 4 + r, n = j * 16 + lr;
          mo[c * ND + n] = f2bf(acc[i][j][r]);
        }
  }
  // ---- phase C: G partials (last iter, bf16 out) ----
  if (doLast) {
    f32x4 acc[4];
#pragma unroll
    for (int j = 0; j < 4; ++j) acc[j] = (f32x4){0.f, 0.f, 0.f, 0.f};
#pragma unroll
    for (int ks = 0; ks < 2; ++ks) {
      s16x8 av = *(const s16x8*)&ptl[w * 16 + lr][ks * 32 + lg * 8];
#pragma unroll
      for (int j = 0; j < 4; ++j) {
        s16x8 bq = *(const s16x8*)&ptl[j * 16 + lr][ks * 32 + lg * 8];
        acc[j] = MFMA16(av, bq, acc[j]);
      }
    }
    u16* go = gp16 + ((size_t)mch * BB + b) * (ND * ND);
#pragma unroll
    for (int j = 0; j < 4; ++j)
#pragma unroll
      for (int r = 0; r < 4; ++r) {
        const int n1 = w * 16 + lg * 4 + r, n2 = j * 16 + lr;
        go[n1 * ND + n2] = f2bf(acc[j][r]);
      }
  }
}

// ---------------- mu reduce + normalize + piw (+ G reduce last iter) -------
__global__ void k_mu_red(const u16* __restrict__ mup16, const float* __restrict__ spb,
                         float* __restrict__ piw, float* __restrict__ mu,
                         u16* __restrict__ mu_t, const u16* __restrict__ gp16,
                         float* __restrict__ G, int doG) {
  const int idx = blockIdx.x * 256 + threadIdx.x;   // grid 256 -> 65536
  const int bb = idx >> 14, c = (idx >> 6) & 255, n = idx & 63;
  float s = 0.f;
#pragma unroll 8
  for (int ch = 0; ch < 64; ++ch)
    s += bf2f(mup16[((size_t)ch * BB + bb) * (IN * ND) + (idx & 16383)]);
  const float v = s / (1e-18f + spb[bb * ND + n]);
  mu[idx] = v;
  mu_t[((size_t)(bb * ND + n)) * IN + c] = f2bf(v);
  if (idx < BB * ND) piw[idx] = spb[idx] * (1.f / (float)WH);
  if (doG && idx < BB * ND * ND) {
    float g = 0.f;
#pragma unroll 8
    for (int ch = 0; ch < 64; ++ch)
      g += bf2f(gp16[(size_t)ch * (BB * ND * ND) + idx]);
    G[idx] = g;
  }
}

// ---------------- GC-A: q = gw@x2, xa = Wa@x2+ba, dv -----------------------
__global__ __launch_bounds__(256) void k_gcA(
    const float* __restrict__ mu, const float* __restrict__ gw,
    const float* __restrict__ Wa, const float* __restrict__ ba,
    const float* __restrict__ Wd, const float* __restrict__ bd,
    float* __restrict__ qbuf, float* __restrict__ xabuf, float* __restrict__ dv) {
  __shared__ float sx2[IN * ND];
  __shared__ float srm[IN];
  const int t = threadIdx.x, blk = blockIdx.x, b = blockIdx.y;
  if (blk < 6) {
    const float* src = mu + (size_t)b * IN * ND;
#pragma unroll
    for (int q4 = 0; q4 < 16; ++q4)
      *(float4*)&sx2[q4 * 1024 + t * 4] = *(const float4*)&src[q4 * 1024 + t * 4];
    __syncthreads();
    const int rg = t >> 4, cg = t & 15;
    const float* W = (blk < 4) ? gw + (size_t)(blk * 64 + rg * 4) * IN
                               : Wa + (size_t)((blk - 4) * 64 + rg * 4) * IN;
    float acc[4][4] = {};
    for (int i4 = 0; i4 < 64; ++i4) {
      float4 xv[4];
#pragma unroll
      for (int e = 0; e < 4; ++e)
        xv[e] = *(const float4*)&sx2[(i4 * 4 + e) * 64 + cg * 4];
#pragma unroll
      for (int rr = 0; rr < 4; ++rr) {
        const float4 w4 = *(const float4*)&W[(size_t)rr * IN + i4 * 4];
        acc[rr][0] += w4.x * xv[0].x + w4.y * xv[1].x + w4.z * xv[2].x + w4.w * xv[3].x;
        acc[rr][1] += w4.x * xv[0].y + w4.y * xv[1].y + w4.z * xv[2].y + w4.w * xv[3].y;
        acc[rr][2] += w4.x * xv[0].z + w4.y * xv[1].z + w4.z * xv[2].z + w4.w * xv[3].z;
        acc[rr][3] += w4.x * xv[0].w + w4.y * xv[1].w + w4.z * xv[2].w + w4.w * xv[3].w;
      }
    }
    if (blk < 4) {
      float* dst = qbuf + (size_t)b * IN * ND + (size_t)(blk * 64 + rg * 4) * ND + cg * 4;
#pragma unroll
      for (int rr = 0; rr < 4; ++rr)
        *(float4*)&dst[(size_t)rr * ND] =
            make_float4(acc[rr][0], acc[rr][1], acc[rr][2], acc[rr][3]);
    } else {
      const int xr = (blk - 4) * 64 + rg * 4;
      float* dst = xabuf + (size_t)b * DCN * ND + (size_t)xr * ND + cg * 4;
#pragma unroll
      for (int rr = 0; rr < 4; ++rr) {
        const float bv = ba[xr + rr];
        *(float4*)&dst[(size_t)rr * ND] =
            make_float4(acc[rr][0] + bv, acc[rr][1] + bv, acc[rr][2] + bv, acc[rr][3] + bv);
      }
    }
  } else {
    {
      const float* row = mu + (size_t)b * IN * ND + (size_t)t * ND;
      float s = 0.f;
#pragma unroll
      for (int n4 = 0; n4 < 16; ++n4) {
        float4 v = *(const float4*)&row[n4 * 4];
        s += v.x + v.y + v.z + v.w;
      }
      srm[t] = s * (1.f / ND);
    }
    __syncthreads();
    if (t < DCN) {
      float a = 0.f;
#pragma unroll
      for (int i4 = 0; i4 < 64; ++i4) {
        float4 w4 = *(const float4*)&Wd[(size_t)t * IN + i4 * 4];
        float4 r4 = *(const float4*)&srm[i4 * 4];
        a += w4.x * r4.x + w4.y * r4.y + w4.z * r4.z + w4.w * r4.w;
      }
      a += bd[t];
      dv[b * DCN + t] = 1.f / (1.f + __expf(-a)) - 0.5f;
    }
  }
}

// ---------------- GC-B + GC-C fused ----------------------------------------
__global__ __launch_bounds__(256) void k_gcBC(
    const float* __restrict__ xabuf, const float* __restrict__ dv,
    const float* __restrict__ qbuf, const float* __restrict__ mu,
    float* __restrict__ x2g) {
  __shared__ float sxa[DCN * ND];
  __shared__ float sA[ND * 65];
  __shared__ float sq[64 * 68];
  __shared__ float sdv[DCN];
  __shared__ float su[ND];
  __shared__ float sdeg[ND];
  const int t = threadIdx.x, qtr = blockIdx.x, b = blockIdx.y;
  {
    const float* src = xabuf + (size_t)b * DCN * ND;
#pragma unroll
    for (int q4 = 0; q4 < 8; ++q4)
      *(float4*)&sxa[q4 * 1024 + t * 4] = *(const float4*)&src[q4 * 1024 + t * 4];
    if (t < DCN) sdv[t] = dv[b * DCN + t];
    const int r = t >> 2, seg = (t & 3) * 16;
    const float* qs = qbuf + (size_t)b * IN * ND + (size_t)(qtr * 64 + r) * ND + seg;
#pragma unroll
    for (int f = 0; f < 4; ++f) {
      float4 v = *(const float4*)&qs[f * 4];
      sq[r * 68 + seg + f * 4 + 0] = v.x; sq[r * 68 + seg + f * 4 + 1] = v.y;
      sq[r * 68 + seg + f * 4 + 2] = v.z; sq[r * 68 + seg + f * 4 + 3] = v.w;
    }
  }
  __syncthreads();
  if (t < ND) {
    float s = 0.f;
    for (int dc = 0; dc < DCN; ++dc) s += sxa[dc * ND + t];
    su[t] = s;
  }
  __syncthreads();
  {
    const int n1g = t >> 4, n2g = t & 15;
    float acc[4][4] = {};
    for (int dc = 0; dc < DCN; ++dc) {
      const float dvv = sdv[dc];
      float4 v1 = *(const float4*)&sxa[dc * ND + n1g * 4];
      const float4 v2 = *(const float4*)&sxa[dc * ND + n2g * 4];
      v1.x *= dvv; v1.y *= dvv; v1.z *= dvv; v1.w *= dvv;
      acc[0][0] += v1.x * v2.x; acc[0][1] += v1.x * v2.y;
      acc[0][2] += v1.x * v2.z; acc[0][3] += v1.x * v2.w;
      acc[1][0] += v1.y * v2.x; acc[1][1] += v1.y * v2.y;
      acc[1][2] += v1.y * v2.z; acc[1][3] += v1.y * v2.w;
      acc[2][0] += v1.z * v2.x; acc[2][1] += v1.z * v2.y;
      acc[2][2] += v1.z * v2.z; acc[2][3] += v1.z * v2.w;
      acc[3][0] += v1.w * v2.x; acc[3][1] += v1.w * v2.y;
      acc[3][2] += v1.w * v2.z; acc[3][3] += v1.w * v2.w;
    }
#pragma unroll
    for (int i = 0; i < 4; ++i) {
      const int n1 = n1g * 4 + i;
      const float u1 = su[n1];
#pragma unroll
      for (int j = 0; j < 4; ++j) {
        const int n2 = n2g * 4 + j;
        const float v = acc[i][j] + 0.5f * u1 * su[n2];
        sA[n1 * 65 + n2] = fmaxf(v, 0.f) + (n1 == n2 ? 1.f : 0.f);
      }
    }
  }
  __syncthreads();
  if (t < ND) {
    float s = 0.f;
    for (int m = 0; m < ND; ++m) s += sA[m * 65 + t];
    sdeg[t] = rsqrtf(s);
  }
  __syncthreads();
  {
    const int n1g = t >> 4, n2g = t & 15;
#pragma unroll
    for (int i = 0; i < 4; ++i) {
      const int n1 = n1g * 4 + i;
      const float dr = sdeg[n1];
#pragma unroll
      for (int e = 0; e < 4; ++e)
        sA[n1 * 65 + n2g * 4 + e] *= dr * sdeg[n2g * 4 + e];
    }
  }
  __syncthreads();
  {
    const int rg = t >> 4, cg2 = t & 15;
    float acc[4][4] = {};
    for (int k = 0; k < ND; ++k) {
      const float4 a4 = *(const float4*)&sA[k * 65 + cg2 * 4];
      float qv[4];
#pragma unroll
      for (int rr = 0; rr < 4; ++rr) qv[rr] = sq[(rg * 4 + rr) * 68 + k];
#pragma unroll
      for (int rr = 0; rr < 4; ++rr) {
        acc[rr][0] += qv[rr] * a4.x; acc[rr][1] += qv[rr] * a4.y;
        acc[rr][2] += qv[rr] * a4.z; acc[rr][3] += qv[rr] * a4.w;
      }
    }
#pragma unroll
    for (int rr = 0; rr < 4; ++rr) {
      const size_t off = (size_t)b * IN * ND + (size_t)(qtr * 64 + rg * 4 + rr) * ND + cg2 * 4;
      const float4 xv = *(const float4*)&mu[off];
      float4 o;
      o.x = fmaxf(acc[rr][0], 0.f) + xv.x; o.y = fmaxf(acc[rr][1], 0.f) + xv.y;
      o.z = fmaxf(acc[rr][2], 0.f) + xv.z; o.w = fmaxf(acc[rr][3], 0.f) + xv.w;
      *(float4*)&x2g[off] = o;
    }
  }
}

// ---------------- dual z-GEMM: z = W @ v (f32) + zb bf16 -------------------
__global__ __launch_bounds__(256) void k_zdual(
    const float* __restrict__ Wo, const float* __restrict__ v1,
    float* __restrict__ z1o, u16* __restrict__ zb1o,
    const float* __restrict__ Wo2, const float* __restrict__ v2,
    float* __restrict__ z2o, u16* __restrict__ zb2o) {
  const float* W = blockIdx.z ? Wo2 : Wo;
  const float* v = blockIdx.z ? v2 : v1;
  float* z  = blockIdx.z ? z2o : z1o;
  u16* zb   = blockIdx.z ? zb2o : zb1o;
  __shared__ float As[16][68];
  __shared__ float Bs[16][64];
  const int t = threadIdx.x, tx = t & 15, ty = t >> 4;
  const int o0 = blockIdx.x * 64, bb = blockIdx.y;
  const int aoo = t >> 2, akq = (t & 3) * 4;
  const int bkk = t >> 4, bnq = (t & 15) * 4;
  float acc[4][4] = {};
  for (int k0 = 0; k0 < IN; k0 += 16) {
    {
      float4 w4 = *(const float4*)&W[(size_t)(o0 + aoo) * IN + k0 + akq];
      As[akq + 0][aoo] = w4.x; As[akq + 1][aoo] = w4.y;
      As[akq + 2][aoo] = w4.z; As[akq + 3][aoo] = w4.w;
    }
    *(float4*)&Bs[bkk][bnq] = *(const float4*)&v[((size_t)bb * IN + k0 + bkk) * ND + bnq];
    __syncthreads();
#pragma unroll
    for (int kk = 0; kk < 16; ++kk) {
      float4 a4 = *(const float4*)&As[kk][ty * 4];
      float4 b4 = *(const float4*)&Bs[kk][tx * 4];
      float ar[4] = {a4.x, a4.y, a4.z, a4.w}, br[4] = {b4.x, b4.y, b4.z, b4.w};
#pragma unroll
      for (int i = 0; i < 4; ++i)
#pragma unroll
        for (int j = 0; j < 4; ++j) acc[i][j] += ar[i] * br[j];
    }
    __syncthreads();
  }
#pragma unroll
  for (int i = 0; i < 4; ++i) {
    float4 r = make_float4(acc[i][0], acc[i][1], acc[i][2], acc[i][3]);
    const size_t off = ((size_t)bb * CH + o0 + ty * 4 + i) * ND + tx * 4;
    *(float4*)&z[off] = r;
    ushort4 h;
    h.x = f2bf(r.x); h.y = f2bf(r.y); h.z = f2bf(r.z); h.w = f2bf(r.w);
    *(ushort4*)&zb[off] = h;
  }
}

// ---------------- BN stats -------------------------------------------------
__global__ __launch_bounds__(256) void k_stats(
    const float* __restrict__ z1, const float* __restrict__ z2,
    const float* __restrict__ sp, const float* __restrict__ G,
    const float* __restrict__ gam, const float* __restrict__ bet,
    const float* __restrict__ gam2, const float* __restrict__ bet2,
    float* __restrict__ abc) {
  const int t = threadIdx.x;
  const int o = blockIdx.x * 4 + (t >> 6), lane = t & 63;
#pragma unroll
  for (int br = 0; br < 2; ++br) {
    const float* z = br ? z2 : z1;
    float macc = 0.f, eacc = 0.f;
    for (int bb = 0; bb < BB; ++bb) {
      const float zv = z[((size_t)bb * CH + o) * ND + lane];
      float s1 = zv * sp[bb * ND + lane];
      const float* Gb = G + (size_t)bb * ND * ND;
      float gz = 0.f;
      for (int k = 0; k < ND; ++k) {
        const float zk = __shfl(zv, k);
        gz += Gb[k * ND + lane] * zk;
      }
      float q = zv * gz;
#pragma unroll
      for (int off = 32; off; off >>= 1) {
        s1 += __shfl_xor(s1, off);
        q  += __shfl_xor(q, off);
      }
      macc += s1; eacc += q;
    }
    const float inv = 1.f / (float)((size_t)BB * WH);
    const float mean = macc * inv;
    const float var  = eacc * inv - mean * mean;
    const float a = (br ? gam2[o] : gam[o]) * rsqrtf(var + 1e-5f);
    const float c = (br ? bet2[o] : bet[o]) - mean * a;
    if (lane == 0) { abc[br * 2 * CH + o] = a; abc[br * 2 * CH + CH + o] = c; }
  }
}

// ---------------- epilogue: MFMA y=z.post^T, BN, residual relus ------------
__global__ __launch_bounds__(256) void k_epi(
    const u16* __restrict__ zb1, const u16* __restrict__ zb2,
    const u16* __restrict__ post, const float* __restrict__ abc,
    const float* __restrict__ x, float* __restrict__ out1, float* __restrict__ out2) {
  const int t = threadIdx.x, w = t >> 6, lr = t & 15, lg = (t >> 4) & 3;
  const int m0 = blockIdx.x * 256 + w * 64, o0 = blockIdx.y * 64, bb = blockIdx.z;
  f32x4 acc1[4][4], acc2[4][4];
#pragma unroll
  for (int i = 0; i < 4; ++i)
#pragma unroll
    for (int j = 0; j < 4; ++j) {
      acc1[i][j] = (f32x4){0.f, 0.f, 0.f, 0.f};
      acc2[i][j] = (f32x4){0.f, 0.f, 0.f, 0.f};
    }
  const u16* z1p = zb1 + ((size_t)bb * CH + o0 + lr) * ND + lg * 8;
  const u16* z2p = zb2 + ((size_t)bb * CH + o0 + lr) * ND + lg * 8;
  const u16* pp  = post + ((size_t)bb * WH + m0 + lr) * ND + lg * 8;
#pragma unroll
  for (int ks = 0; ks < 2; ++ks) {
    s16x8 a1[4], a2[4], bq[4];
#pragma unroll
    for (int i = 0; i < 4; ++i) {
      a1[i] = ld8(z1p + i * 16 * ND + ks * 32);
      a2[i] = ld8(z2p + i * 16 * ND + ks * 32);
    }
#pragma unroll
    for (int j = 0; j < 4; ++j) bq[j] = ld8(pp + j * 16 * ND + ks * 32);
#pragma unroll
    for (int i = 0; i < 4; ++i)
#pragma unroll
      for (int j = 0; j < 4; ++j) {
        acc1[i][j] = MFMA16(a1[i], bq[j], acc1[i][j]);
        acc2[i][j] = MFMA16(a2[i], bq[j], acc2[i][j]);
      }
  }
#pragma unroll
  for (int i = 0; i < 4; ++i)
#pragma unroll
    for (int r = 0; r < 4; ++r) {
      const int o = o0 + i * 16 + lg * 4 + r;
      const float a1v = abc[o], c1v = abc[CH + o];
      const float a2v = abc[2 * CH + o], c2v = abc[3 * CH + o];
      const size_t base = ((size_t)bb * CH + o) * WH + m0 + lr;
#pragma unroll
      for (int j = 0; j < 4; ++j) {
        const size_t off = base + j * 16;
        const float xv = x[off];
        out1[off] = fmaxf(fmaxf(a1v * acc1[i][j][r] + c1v, 0.f) + xv, 0.f);
        out2[off] = fmaxf(fmaxf(a2v * acc2[i][j][r] + c2v, 0.f) + xv, 0.f);
      }
    }
}

// ---------------------------------------------------------------------------
extern "C" void kernel_launch(void* const* d_in, const int* in_sizes, int n_in,
                              void* d_out, int out_size, void* d_ws, size_t ws_size,
                              hipStream_t stream) {
  (void)in_sizes; (void)n_in; (void)out_size; (void)ws_size;
  const float* x    = (const float*)d_in[0];
  const float* Win  = (const float*)d_in[1];
  const float* bin  = (const float*)d_in[2];
  const float* mp   = (const float*)d_in[3];
  const float* pi0  = (const float*)d_in[4];
  const float* Wa   = (const float*)d_in[5];
  const float* ba   = (const float*)d_in[6];
  const float* Wd   = (const float*)d_in[7];
  const float* bd   = (const float*)d_in[8];
  const float* gw   = (const float*)d_in[9];
  const float* Wo   = (const float*)d_in[10];
  const float* gam  = (const float*)d_in[12];
  const float* bet  = (const float*)d_in[13];
  const float* Wo2  = (const float*)d_in[14];
  const float* gam2 = (const float*)d_in[16];
  const float* bet2 = (const float*)d_in[17];

  char* ob = (char*)d_out;
  char* wp = (char*)d_ws;
  // scratch in d_out (dead before k_epi writes outputs):
  u16*   mup16 = (u16*)(ob + 0);          // 8.4 MB (64 chunks, bf16)
  u16*   gp16  = (u16*)(ob + 8388608);    // 2 MB (bf16)
  float* z1    = (float*)(ob + 10485760); // 1 MB
  float* z2    = (float*)(ob + 11534336); // 1 MB
  // ws (~21.7 MB; x1 region unused):
  u16*   x1t   = (u16*)(wp + 8388608);     // 8.4 MB [b][m][c]
  u16*   Winb  = (u16*)(wp + 16777216);    // 0.5 MB
  u16*   mu_t  = (u16*)(wp + 17301504);    // 128 KB [b][n][c]
  u16*   pmn   = (u16*)(wp + 17432576);    // 2 MB [b][m][n]
  float* mu    = (float*)(wp + 19529728);  // 256 KB [b][c][n]
  float* x2g   = (float*)(wp + 19791872);  // 256 KB
  u16*   zb1   = (u16*)(wp + 20054016);    // 0.5 MB
  u16*   zb2   = (u16*)(wp + 20578304);    // 0.5 MB
  float* sp3   = (float*)(wp + 21102592);  // 3 KB
  float* piw   = (float*)(wp + 21105664);  // 1 KB
  float* abc   = (float*)(wp + 21106688);  // 16 KB
  float* G     = (float*)(wp + 21123072);  // 64 KB
  float* qbuf  = (float*)(wp + 21188608);  // 256 KB
  float* xabuf = (float*)(wp + 21450752);  // 128 KB
  float* dvb   = (float*)(wp + 21581824);  // 2 KB
  float* out1  = (float*)d_out;
  float* out2  = out1 + TOT;

  k_init<<<dim3(1284), 256, 0, stream>>>(Win, mp, pi0, Winb, mu_t, piw, sp3);
  k_x1<<<dim3(64, BB), 512, 0, stream>>>(x, Winb, bin, x1t);
  for (int it = 0; it < 3; ++it) {
    float* spb = sp3 + it * 256;
    const int doLast = (it == 2);
    k_em<<<dim3(64, BB), 256, 0, stream>>>(x1t, mu_t, piw, spb, pmn,
                                           mup16, gp16, doLast);
    k_mu_red<<<dim3(256), 256, 0, stream>>>(mup16, spb, piw, mu, mu_t,
                                            gp16, G, doLast);
  }
  k_gcA<<<dim3(7, BB), 256, 0, stream>>>(mu, gw, Wa, ba, Wd, bd, qbuf, xabuf, dvb);
  k_gcBC<<<dim3(4, BB), 256, 0, stream>>>(xabuf, dvb, qbuf, mu, x2g);
  k_zdual<<<dim3(16, BB, 2), 256, 0, stream>>>(Wo, x2g, z1, zb1, Wo2, mu, z2, zb2);
  k_stats<<<dim3(256), 256, 0, stream>>>(z1, z2, sp3 + 512, G, gam, bet, gam2, bet2, abc);
  k_epi<<<dim3(16, 16, BB), 256, 0, stream>>>(zb1, zb2, pmn, abc, x, out1, out2);
}